// Round 3
// baseline (11.663 us; speedup 1.0000x reference)
//
#include <hip/hip_runtime.h>
#include <hip/hip_bf16.h>

// Embedding gather: out[token, :] = weight[x[token], :]
// x: [4096] int32, weight: [32000, 512] fp32, out: [4096, 512] fp32.
//
// ILP-8 variant: each thread owns 8 float4 of one row (16 threads per row,
// cols c, c+16, ..., c+112 -> 256B-apart immediate offsets). A wave issues
// 8 independent gathers before its first s_waitcnt, shortening the
// per-wave serial chain to idx_load + one gather latency for 8 results.
// Non-temporal stores: out is write-once, keep it out of L2/L3 so the
// gathered weight rows stay cache-resident across graph replays.

typedef float f32x4 __attribute__((ext_vector_type(4)));

__global__ __launch_bounds__(128) void emb_gather_ilp8(
    const int* __restrict__ x,
    const f32x4* __restrict__ w4,      // weight as [V][128] float4
    f32x4* __restrict__ out4,          // out as [T][128] float4
    int nthreads)                      // T * 16  (8 float4 per thread)
{
    int t = blockIdx.x * blockDim.x + threadIdx.x;
    if (t >= nthreads) return;

    int row = t >> 4;                  // token index (16 threads per row)
    int col = t & 15;                  // base float4 column

    int idx = x[row];                  // 16 KB table, L2-hot across replays

    const f32x4* __restrict__ src = w4 + (size_t)idx * 128 + col;
    f32x4* __restrict__ dst       = out4 + (size_t)row * 128 + col;

    // 8 independent loads: one vaddr + 7 immediate offsets (256B apart)
    f32x4 v0 = src[0];
    f32x4 v1 = src[16];
    f32x4 v2 = src[32];
    f32x4 v3 = src[48];
    f32x4 v4 = src[64];
    f32x4 v5 = src[80];
    f32x4 v6 = src[96];
    f32x4 v7 = src[112];

    __builtin_nontemporal_store(v0, dst + 0);
    __builtin_nontemporal_store(v1, dst + 16);
    __builtin_nontemporal_store(v2, dst + 32);
    __builtin_nontemporal_store(v3, dst + 48);
    __builtin_nontemporal_store(v4, dst + 64);
    __builtin_nontemporal_store(v5, dst + 80);
    __builtin_nontemporal_store(v6, dst + 96);
    __builtin_nontemporal_store(v7, dst + 112);
}

extern "C" void kernel_launch(void* const* d_in, const int* in_sizes, int n_in,
                              void* d_out, int out_size, void* d_ws, size_t ws_size,
                              hipStream_t stream) {
    const int*   x = (const int*)d_in[0];     // [4096] indices
    const float* w = (const float*)d_in[1];   // [32000 * 512] fp32

    int n_tokens = in_sizes[0];               // 4096
    int nthreads = n_tokens * 16;             // 65536 threads, 8 float4 each

    int block = 128;
    int grid  = (nthreads + block - 1) / block; // 512 blocks

    emb_gather_ilp8<<<grid, block, 0, stream>>>(
        x,
        reinterpret_cast<const f32x4*>(w),
        reinterpret_cast<f32x4*>(d_out),
        nthreads);
}

// Round 4
// 10.446 us; speedup vs baseline: 1.1165x; 1.1165x over previous
//
#include <hip/hip_runtime.h>
#include <hip/hip_bf16.h>

// Embedding gather: out[token, :] = weight[x[token], :]
// x: [4096] int32, weight: [32000, 512] fp32, out: [4096, 512] fp32.
//
// Best-known config (R2): ILP-4, 131072 threads (2048 waves = 8/CU),
// block=256. Each thread owns 4 float4 of one row (cols c, c+32, c+64,
// c+96 -> 512B-apart immediate offsets): one idx load then 4 independent
// gathers outstanding before the first s_waitcnt.
//
// A/B vs R2: plain stores instead of non-temporal. Output retires into
// L2 (8 MiB << 32 MiB aggregate) instead of draining to HBM before
// kernel end; everything else identical.

typedef float f32x4 __attribute__((ext_vector_type(4)));

__global__ __launch_bounds__(256) void emb_gather_ilp4_plain(
    const int* __restrict__ x,
    const f32x4* __restrict__ w4,      // weight as [V][128] float4
    f32x4* __restrict__ out4,          // out as [T][128] float4
    int nthreads)                      // T * 32  (4 float4 per thread)
{
    int t = blockIdx.x * blockDim.x + threadIdx.x;
    if (t >= nthreads) return;

    int row = t >> 5;                  // token index (32 threads per row)
    int col = t & 31;                  // base float4 column

    int idx = x[row];                  // 16 KB table, L2-hot after first waves

    const f32x4* __restrict__ src = w4 + (size_t)idx * 128 + col;
    f32x4* __restrict__ dst       = out4 + (size_t)row * 128 + col;

    // 4 independent loads: one vaddr + 3 immediate offsets (512/1024/1536 B)
    f32x4 a = src[0];
    f32x4 b = src[32];
    f32x4 c = src[64];
    f32x4 d = src[96];

    dst[0]  = a;
    dst[32] = b;
    dst[64] = c;
    dst[96] = d;
}

extern "C" void kernel_launch(void* const* d_in, const int* in_sizes, int n_in,
                              void* d_out, int out_size, void* d_ws, size_t ws_size,
                              hipStream_t stream) {
    const int*   x = (const int*)d_in[0];     // [4096] indices
    const float* w = (const float*)d_in[1];   // [32000 * 512] fp32

    int n_tokens = in_sizes[0];               // 4096
    int nthreads = n_tokens * 32;             // 131072 threads, 4 float4 each

    int block = 256;
    int grid  = (nthreads + block - 1) / block; // 512 blocks

    emb_gather_ilp4_plain<<<grid, block, 0, stream>>>(
        x,
        reinterpret_cast<const f32x4*>(w),
        reinterpret_cast<f32x4*>(d_out),
        nthreads);
}